// Round 1
// 2030.212 us; speedup vs baseline: 1.4231x; 1.4231x over previous
//
#include <hip/hip_runtime.h>
#include <stdint.h>

#define B_ 128
#define T_ 512
#define H_ 256
#define CH 128           // timesteps per chunk (xz slab = 32 MB)
#define RB 32            // rec blocks per layer (4 batch rows each)

typedef short bf16x8 __attribute__((ext_vector_type(8)));   // 8 bf16 = 4 VGPRs
typedef float f32x4 __attribute__((ext_vector_type(4)));
typedef int   i32x4 __attribute__((ext_vector_type(4)));

__device__ __forceinline__ unsigned short f2bf(float f) {
    union { float f; uint32_t u; } v; v.f = f;
    uint32_t u = v.u;
    return (unsigned short)((u + 0x7FFFu + ((u >> 16) & 1u)) >> 16);  // RNE
}
__device__ __forceinline__ float bf2f(unsigned int b) {
    union { uint32_t u; float f; } v; v.u = (b & 0xFFFFu) << 16; return v.f;
}
__device__ __forceinline__ float sigm(float x) { return 1.0f / (1.0f + __expf(-x)); }
__device__ __forceinline__ float tanh_(float x) { return 1.0f - 2.0f / (__expf(2.0f * x) + 1.0f); }

// ---- prep: x[b][t][f] fp32 -> xbf[t][b][f] bf16 ----
__global__ void k_prep_x(const float* __restrict__ x, unsigned short* __restrict__ xbf) {
    int idx = blockIdx.x * blockDim.x + threadIdx.x;   // over B*T*F/4
    int f4 = idx & 63;
    int t = (idx >> 6) & 511;
    int b = idx >> 15;
    float4 v = *(const float4*)(x + ((size_t)b * T_ + t) * H_ + f4 * 4);
    ushort4 o;
    o.x = f2bf(v.x); o.y = f2bf(v.y); o.z = f2bf(v.z); o.w = f2bf(v.w);
    *(ushort4*)(xbf + ((size_t)t * B_ + b) * H_ + f4 * 4) = o;
}

// ---- prep: in [256][1024] fp32 -> out[col][k] bf16 ----
__global__ void k_prep_w(const float* __restrict__ in, unsigned short* __restrict__ out) {
    int idx = blockIdx.x * blockDim.x + threadIdx.x;   // 1024*256
    int k = idx & 255; int col = idx >> 8;
    out[(size_t)col * 256 + k] = f2bf(in[(size_t)k * 1024 + col]);
}

__global__ void k_prep_wd(const float* __restrict__ Wd, unsigned short* __restrict__ Wdt) {
    int idx = blockIdx.x * blockDim.x + threadIdx.x;   // 256*256
    int k = idx & 255; int col = idx >> 8;
    Wdt[(size_t)col * 256 + k] = f2bf(Wd[(size_t)k * 256 + col]);
}

// ---- absmax of U (262144 fp32) -> slot (float bits via int atomicMax) ----
__global__ void k_umax(const float* __restrict__ in, float* __restrict__ slot) {
    float m = 0.f;
    for (int i = blockIdx.x * blockDim.x + threadIdx.x; i < 262144; i += gridDim.x * blockDim.x)
        m = fmaxf(m, fabsf(in[i]));
#pragma unroll
    for (int off = 1; off < 64; off <<= 1) m = fmaxf(m, __shfl_xor(m, off));
    if ((threadIdx.x & 63) == 0) atomicMax((int*)slot, __float_as_int(m));
}

// ---- quantize U: in [256][1024] fp32 -> out[col][k] i8 ----
__global__ void k_prep_u(const float* __restrict__ in, const float* __restrict__ umax,
                         signed char* __restrict__ out) {
    int idx = blockIdx.x * blockDim.x + threadIdx.x;   // 1024*256
    int k = idx & 255; int col = idx >> 8;
    float s = 127.f / *umax;
    float v = in[(size_t)k * 1024 + col] * s;
    out[(size_t)col * 256 + k] = (signed char)__float2int_rn(fminf(fmaxf(v, -127.f), 127.f));
}

// ---- input-projection GEMM for one 128-t chunk:
// A[tl][128][256] bf16 x Bt[1024][256] + bias -> xz swizzled bf16:
// elem addr = tl*131072 + rg*16384 + wr*4096 + n*256 + (quad*16+l15)*4 + r
// holding z[row = rg*16 + quad*4 + r][col = g*256 + wr*64 + s*16 + l15], n = g*4+s.
__global__ __launch_bounds__(256, 2) void k_gemm(
    const unsigned short* __restrict__ A, const unsigned short* __restrict__ Bt,
    const float* __restrict__ bias, unsigned short* __restrict__ xz) {
    const int tl = blockIdx.x >> 2, nq = blockIdx.x & 3;
    const int tid = threadIdx.x;
    const int wave = tid >> 6, lane = tid & 63, quad = lane >> 4, l15 = lane & 15;
    const f32x4 zero = {0.f, 0.f, 0.f, 0.f};
    f32x4 acc[2][16];
#pragma unroll
    for (int m = 0; m < 2; ++m)
#pragma unroll
        for (int n = 0; n < 16; ++n) acc[m][n] = zero;

#pragma unroll
    for (int kt = 0; kt < 8; ++kt) {
        bf16x8 a0 = *(const bf16x8*)(A + ((size_t)(tl * 128 + wave * 32 + l15)) * 256 + kt * 32 + quad * 8);
        bf16x8 a1 = *(const bf16x8*)(A + ((size_t)(tl * 128 + wave * 32 + 16 + l15)) * 256 + kt * 32 + quad * 8);
#pragma unroll
        for (int ntl = 0; ntl < 16; ++ntl) {
            bf16x8 b = *(const bf16x8*)(Bt + ((size_t)(nq * 256 + ntl * 16 + l15)) * 256 + kt * 32 + quad * 8);
            acc[0][ntl] = __builtin_amdgcn_mfma_f32_16x16x32_bf16(a0, b, acc[0][ntl], 0, 0, 0);
            acc[1][ntl] = __builtin_amdgcn_mfma_f32_16x16x32_bf16(a1, b, acc[1][ntl], 0, 0, 0);
        }
    }
#pragma unroll
    for (int ntl = 0; ntl < 16; ++ntl) {
        int c0 = nq * 256 + ntl * 16;
        float bv = bias[c0 + l15];
        int wr = ntl >> 2, s = ntl & 3;
        int n = nq * 4 + s;
#pragma unroll
        for (int mt = 0; mt < 2; ++mt) {
            int rg = wave * 2 + mt;
            unsigned long long pk = 0;
#pragma unroll
            for (int r = 0; r < 4; ++r)
                pk |= ((unsigned long long)f2bf(acc[mt][ntl][r] + bv)) << (16 * r);
            *(unsigned long long*)(xz + (((size_t)(tl * 8 + rg) * 4 + wr) * 16 + n) * 256 + lane * 4) = pk;
        }
    }
}

// ---- LSTM recurrence chunk: i8 MFMA, U register-resident, 8 waves / 2 per SIMD ----
// grid = 32 blocks x 512 thr; block owns batch rows [4*blk, 4*blk+4).
// Wave w covers cols (w>>1)*64 + ((w&1)*2+s)*16 + l15 (s=0,1) of each gate g;
// n-tiles n = g*2+s  ->  old-layout tile n_old = g*4 + (w&1)*2 + s.
// 8 waves -> Bf = 128 VGPR/wave -> 2 waves/SIMD co-resident: latencies cross-hide.
__global__ __launch_bounds__(512, 2) void k_rec(
    const signed char* __restrict__ Ui8,     // [1024][256] i8
    const unsigned short* __restrict__ xz,   // chunk, swizzled
    const float* __restrict__ uscale,
    unsigned short* __restrict__ hout,       // [T][128][256] bf16
    float* __restrict__ cstate,              // [32][1024] f32
    int t0) {
    __shared__ __align__(16) int zbuf[4096];                 // [w][n][l15][r] = 16 KB
    __shared__ __align__(16) signed char hbuf[2][16 * 272];  // i8 h ping-pong
    const int blk = blockIdx.x;
    const int tid = threadIdx.x;
    const int w = tid >> 6, lane = tid & 63, quad = lane >> 4, l15 = lane & 15;
    const int sh = quad * 16;
    const int wr = w >> 1;                       // old wave index 0..3
    const int whalf = w & 1;                     // which s-pair of the old wave
    const int colbase = wr * 64 + whalf * 32;    // + s*16 + l15 gives gate-local col

    // U fragments: 8 n-tiles x 4 kt x int4 = 128 VGPR, resident all steps
    i32x4 Bf[8][4];
#pragma unroll
    for (int n = 0; n < 8; ++n) {
        int col = (n >> 1) * 256 + colbase + (n & 1) * 16 + l15;
#pragma unroll
        for (int kt = 0; kt < 4; ++kt)
            Bf[n][kt] = *(const i32x4*)(Ui8 + (size_t)col * 256 + kt * 64 + quad * 16);
    }

    // zero both h buffers (rows 4..15 stay zero forever)
    for (int i = tid; i < 2176; i += 512) ((int*)hbuf)[i] = 0;

    float cst[2];
    if (t0 > 0) {
#pragma unroll
        for (int s = 0; s < 2; ++s) {
            int col = colbase + s * 16 + l15;
            float h = bf2f(hout[((size_t)(t0 - 1) * 128 + blk * 4 + quad) * 256 + col]);
            hbuf[0][quad * 272 + col] = (signed char)__float2int_rn(h * 127.f);
            cst[s] = cstate[(size_t)blk * 1024 + tid * 2 + s];
        }
    } else {
        cst[0] = 0.f; cst[1] = 0.f;
    }
    const float SUH = (*uscale) * (1.f / 16129.f);   // (umax/127) * (1/127)
    __syncthreads();

    const i32x4 zeroi = {0, 0, 0, 0};
    int p = 0;
#pragma unroll 1
    for (int tl = 0; tl < CH; ++tl) {
        // xz loads: no dependency, fire early (latency hidden behind MFMA)
        const unsigned short* xb = xz + (size_t)tl * 131072 + (blk >> 2) * 16384
                                      + wr * 4096 + (blk & 3) * 64 + l15 * 4;
        unsigned long long xu[8];
#pragma unroll
        for (int n = 0; n < 8; ++n) {
            int n_old = (n >> 1) * 4 + whalf * 2 + (n & 1);
            xu[n] = *(const unsigned long long*)(xb + n_old * 256);
        }

        // A fragments from i8 h ping-pong (rows 4..15 are zero padding)
        const signed char* hb = hbuf[p];
        i32x4 Af[4];
#pragma unroll
        for (int kt = 0; kt < 4; ++kt)
            Af[kt] = *(const i32x4*)(hb + l15 * 272 + kt * 64 + quad * 16);

        i32x4 acc[8];
#pragma unroll
        for (int n = 0; n < 8; ++n) acc[n] = zeroi;
#pragma unroll
        for (int kt = 0; kt < 4; ++kt) {
            i32x4 a = Af[kt];
#pragma unroll
            for (int n = 0; n < 8; ++n)
                acc[n] = __builtin_amdgcn_mfma_i32_16x16x64_i8(a, Bf[n][kt], acc[n], 0, 0, 0);
        }

        // z-exchange (wave-local: writer quad0 lanes, readers all lanes)
        if (quad == 0) {
#pragma unroll
            for (int n = 0; n < 8; ++n)
                *(i32x4*)(zbuf + ((w * 8 + n) * 16 + l15) * 4) = acc[n];
        }
        float zv[8];
#pragma unroll
        for (int n = 0; n < 8; ++n) {
            int zi = zbuf[((w * 8 + n) * 16 + l15) * 4 + quad];
            zv[n] = (float)zi * SUH + bf2f((unsigned int)(xu[n] >> sh));
        }

        // gates: this lane owns (row = quad, cols colbase + s*16 + l15)
        unsigned short* hO = hout + ((size_t)((t0 + tl) * 128 + blk * 4 + quad)) * 256 + colbase + l15;
        signed char* hw = hbuf[p ^ 1];
#pragma unroll
        for (int s = 0; s < 2; ++s) {
            float c = sigm(zv[2 + s]) * cst[s] + sigm(zv[s]) * tanh_(zv[4 + s]);
            cst[s] = c;
            float h = sigm(zv[6 + s]) * tanh_(c);
            hO[s * 16] = f2bf(h);
            hw[quad * 272 + colbase + s * 16 + l15] = (signed char)__float2int_rn(h * 127.f);
        }
        __syncthreads();
        p ^= 1;
    }
#pragma unroll
    for (int s = 0; s < 2; ++s)
        cstate[(size_t)blk * 1024 + tid * 2 + s] = cst[s];
}

// ---- Dense(tanh) + LayerNorm, one block per t (128 rows), full N=256 in regs ----
__global__ __launch_bounds__(256, 2) void k_dense_ln(
    const unsigned short* __restrict__ h2buf, const unsigned short* __restrict__ Wdt,
    const float* __restrict__ bd, const float* __restrict__ gamma,
    const float* __restrict__ beta, float* __restrict__ out) {
    const int t = blockIdx.x;
    const int tid = threadIdx.x;
    const int wave = tid >> 6, lane = tid & 63, quad = lane >> 4, l15 = lane & 15;
    const unsigned short* A = h2buf + (size_t)t * B_ * H_;
    const f32x4 zero = {0.f, 0.f, 0.f, 0.f};

    f32x4 acc[2][16];
#pragma unroll
    for (int m = 0; m < 2; ++m)
#pragma unroll
        for (int n = 0; n < 16; ++n) acc[m][n] = zero;

#pragma unroll
    for (int kt = 0; kt < 8; ++kt) {
        bf16x8 a[2];
#pragma unroll
        for (int m = 0; m < 2; ++m) {
            int row = wave * 32 + m * 16 + l15;
            a[m] = *(const bf16x8*)(A + (size_t)row * H_ + kt * 32 + quad * 8);
        }
#pragma unroll
        for (int n = 0; n < 16; ++n) {
            bf16x8 b = *(const bf16x8*)(Wdt + (size_t)(n * 16 + l15) * H_ + kt * 32 + quad * 8);
            acc[0][n] = __builtin_amdgcn_mfma_f32_16x16x32_bf16(a[0], b, acc[0][n], 0, 0, 0);
            acc[1][n] = __builtin_amdgcn_mfma_f32_16x16x32_bf16(a[1], b, acc[1][n], 0, 0, 0);
        }
    }

    float gm[16], bt[16], bdv[16];
#pragma unroll
    for (int n = 0; n < 16; ++n) {
        int c = n * 16 + l15;
        gm[n] = gamma[c]; bt[n] = beta[c]; bdv[n] = bd[c];
    }
#pragma unroll
    for (int m = 0; m < 2; ++m) {
#pragma unroll
        for (int r = 0; r < 4; ++r) {
            float v[16], s = 0.f, sq = 0.f;
#pragma unroll
            for (int n = 0; n < 16; ++n) {
                float x = tanh_(acc[m][n][r] + bdv[n]);
                v[n] = x; s += x; sq += x * x;
            }
#pragma unroll
            for (int off = 1; off < 16; off <<= 1) {
                s += __shfl_xor(s, off);
                sq += __shfl_xor(sq, off);
            }
            float mu = s * (1.f / 256.f);
            float var = sq * (1.f / 256.f) - mu * mu;
            float rs = rsqrtf(var + 1e-3f);
            int row = wave * 32 + m * 16 + quad * 4 + r;   // batch index
            float* po = out + (size_t)row * (T_ * H_) + (size_t)t * H_;
#pragma unroll
            for (int n = 0; n < 16; ++n)
                po[n * 16 + l15] = (v[n] - mu) * rs * gm[n] + bt[n];
        }
    }
}

extern "C" void kernel_launch(void* const* d_in, const int* in_sizes, int n_in,
                              void* d_out, int out_size, void* d_ws, size_t ws_size,
                              hipStream_t stream) {
    const float* x     = (const float*)d_in[0];
    const float* W0    = (const float*)d_in[1];
    const float* U0    = (const float*)d_in[2];
    const float* b0    = (const float*)d_in[3];
    const float* W1    = (const float*)d_in[4];
    const float* U1    = (const float*)d_in[5];
    const float* b1    = (const float*)d_in[6];
    const float* Wd    = (const float*)d_in[7];
    const float* bd    = (const float*)d_in[8];
    const float* gamma = (const float*)d_in[9];
    const float* beta  = (const float*)d_in[10];
    float* out = (float*)d_out;

    char* ws = (char*)d_ws;
    unsigned short* buf0 = (unsigned short*)(ws);                  // 32 MB: xbf, later h2
    unsigned short* xzs  = (unsigned short*)(ws + (32u << 20));    // 32 MB: per-chunk xz
    unsigned short* h1   = (unsigned short*)(ws + (64u << 20));    // 32 MB
    unsigned short* Wt0  = (unsigned short*)(ws + (96u << 20));            // 512 KB
    unsigned short* Wt1  = (unsigned short*)(ws + (96u << 20) + 524288);   // 512 KB
    signed char*    Ui0  = (signed char*)  (ws + (96u << 20) + 1048576);   // 256 KB
    signed char*    Ui1  = (signed char*)  (ws + (96u << 20) + 1310720);   // 256 KB
    unsigned short* Wdt  = (unsigned short*)(ws + (96u << 20) + 1572864);  // 128 KB
    float*          sc   = (float*)        (ws + (96u << 20) + 1703936);   // 2 slots
    float*          cbuf = (float*)        (ws + (96u << 20) + 1704448);   // 128 KB

    hipMemsetAsync(sc, 0, 64, stream);
    k_prep_x<<<16384, 256, 0, stream>>>(x, buf0);
    k_prep_w<<<1024, 256, 0, stream>>>(W0, Wt0);
    k_prep_w<<<1024, 256, 0, stream>>>(W1, Wt1);
    k_prep_wd<<<256, 256, 0, stream>>>(Wd, Wdt);
    k_umax<<<256, 256, 0, stream>>>(U0, sc);
    k_umax<<<256, 256, 0, stream>>>(U1, sc + 1);
    k_prep_u<<<1024, 256, 0, stream>>>(U0, sc, Ui0);
    k_prep_u<<<1024, 256, 0, stream>>>(U1, sc + 1, Ui1);

    for (int c = 0; c < 4; ++c) {
        k_gemm<<<CH * 4, 256, 0, stream>>>(buf0 + (size_t)c * CH * 32768, Wt0, b0, xzs);
        k_rec<<<RB, 512, 0, stream>>>(Ui0, xzs, sc, h1, cbuf, c * CH);
    }
    for (int c = 0; c < 4; ++c) {
        k_gemm<<<CH * 4, 256, 0, stream>>>(h1 + (size_t)c * CH * 32768, Wt1, b1, xzs);
        k_rec<<<RB, 512, 0, stream>>>(Ui1, xzs, sc + 1, buf0, cbuf, c * CH);
    }
    k_dense_ln<<<512, 256, 0, stream>>>(buf0, Wdt, bd, gamma, beta, out);
}

// Round 2
// 1768.456 us; speedup vs baseline: 1.6337x; 1.1480x over previous
//
#include <hip/hip_runtime.h>
#include <stdint.h>

#define B_ 128
#define T_ 512
#define H_ 256
#define CH 128           // timesteps per chunk (xz slab = 32 MB)
#define RB 32            // rec blocks per layer (4 batch rows each)
#define CS ((size_t)CH * 32768)   // chunk stride in shorts (8 MB)

typedef short bf16x8 __attribute__((ext_vector_type(8)));   // 8 bf16 = 4 VGPRs
typedef float f32x4 __attribute__((ext_vector_type(4)));
typedef int   i32x4 __attribute__((ext_vector_type(4)));

__device__ __forceinline__ unsigned short f2bf(float f) {
    union { float f; uint32_t u; } v; v.f = f;
    uint32_t u = v.u;
    return (unsigned short)((u + 0x7FFFu + ((u >> 16) & 1u)) >> 16);  // RNE
}
__device__ __forceinline__ float bf2f(unsigned int b) {
    union { uint32_t u; float f; } v; v.u = (b & 0xFFFFu) << 16; return v.f;
}
__device__ __forceinline__ float sigm(float x) { return 1.0f / (1.0f + __expf(-x)); }
__device__ __forceinline__ float tanh_(float x) { return 1.0f - 2.0f / (__expf(2.0f * x) + 1.0f); }

// ---- prep: x[b][t][f] fp32 -> xbf[t][b][f] bf16 ----
__global__ void k_prep_x(const float* __restrict__ x, unsigned short* __restrict__ xbf) {
    int idx = blockIdx.x * blockDim.x + threadIdx.x;   // over B*T*F/4
    int f4 = idx & 63;
    int t = (idx >> 6) & 511;
    int b = idx >> 15;
    float4 v = *(const float4*)(x + ((size_t)b * T_ + t) * H_ + f4 * 4);
    ushort4 o;
    o.x = f2bf(v.x); o.y = f2bf(v.y); o.z = f2bf(v.z); o.w = f2bf(v.w);
    *(ushort4*)(xbf + ((size_t)t * B_ + b) * H_ + f4 * 4) = o;
}

// ---- prep: in [256][1024] fp32 -> out[col][k] bf16 ----
__global__ void k_prep_w(const float* __restrict__ in, unsigned short* __restrict__ out) {
    int idx = blockIdx.x * blockDim.x + threadIdx.x;   // 1024*256
    int k = idx & 255; int col = idx >> 8;
    out[(size_t)col * 256 + k] = f2bf(in[(size_t)k * 1024 + col]);
}

__global__ void k_prep_wd(const float* __restrict__ Wd, unsigned short* __restrict__ Wdt) {
    int idx = blockIdx.x * blockDim.x + threadIdx.x;   // 256*256
    int k = idx & 255; int col = idx >> 8;
    Wdt[(size_t)col * 256 + k] = f2bf(Wd[(size_t)k * 256 + col]);
}

// ---- absmax of U (262144 fp32) -> slot (float bits via int atomicMax) ----
__global__ void k_umax(const float* __restrict__ in, float* __restrict__ slot) {
    float m = 0.f;
    for (int i = blockIdx.x * blockDim.x + threadIdx.x; i < 262144; i += gridDim.x * blockDim.x)
        m = fmaxf(m, fabsf(in[i]));
#pragma unroll
    for (int off = 1; off < 64; off <<= 1) m = fmaxf(m, __shfl_xor(m, off));
    if ((threadIdx.x & 63) == 0) atomicMax((int*)slot, __float_as_int(m));
}

// ---- quantize U: in [256][1024] fp32 -> out[col][k] i8 ----
__global__ void k_prep_u(const float* __restrict__ in, const float* __restrict__ umax,
                         signed char* __restrict__ out) {
    int idx = blockIdx.x * blockDim.x + threadIdx.x;   // 1024*256
    int k = idx & 255; int col = idx >> 8;
    float s = 127.f / *umax;
    float v = in[(size_t)k * 1024 + col] * s;
    out[(size_t)col * 256 + k] = (signed char)__float2int_rn(fminf(fmaxf(v, -127.f), 127.f));
}

// ================= fused-kernel device paths =================

// ---- input-projection GEMM path, one "old block" ob = (tl, nq), tid 0..255 ----
// A[tl][128][256] bf16 x Bt[1024][256] + bias -> xz swizzled bf16:
// elem addr = tl*131072 + rg*16384 + wr*4096 + n*256 + (quad*16+l15)*4 + r
__device__ __forceinline__ void gemm_path(
    int ob, int tid,
    const unsigned short* __restrict__ A, const unsigned short* __restrict__ Bt,
    const float* __restrict__ bias, unsigned short* __restrict__ xz) {
    const int tl = ob >> 2, nq = ob & 3;
    const int wave = tid >> 6, lane = tid & 63, quad = lane >> 4, l15 = lane & 15;
    const f32x4 zero = {0.f, 0.f, 0.f, 0.f};
    f32x4 acc[2][16];
#pragma unroll
    for (int m = 0; m < 2; ++m)
#pragma unroll
        for (int n = 0; n < 16; ++n) acc[m][n] = zero;

#pragma unroll
    for (int kt = 0; kt < 8; ++kt) {
        bf16x8 a0 = *(const bf16x8*)(A + ((size_t)(tl * 128 + wave * 32 + l15)) * 256 + kt * 32 + quad * 8);
        bf16x8 a1 = *(const bf16x8*)(A + ((size_t)(tl * 128 + wave * 32 + 16 + l15)) * 256 + kt * 32 + quad * 8);
#pragma unroll
        for (int ntl = 0; ntl < 16; ++ntl) {
            bf16x8 b = *(const bf16x8*)(Bt + ((size_t)(nq * 256 + ntl * 16 + l15)) * 256 + kt * 32 + quad * 8);
            acc[0][ntl] = __builtin_amdgcn_mfma_f32_16x16x32_bf16(a0, b, acc[0][ntl], 0, 0, 0);
            acc[1][ntl] = __builtin_amdgcn_mfma_f32_16x16x32_bf16(a1, b, acc[1][ntl], 0, 0, 0);
        }
    }
#pragma unroll
    for (int ntl = 0; ntl < 16; ++ntl) {
        int c0 = nq * 256 + ntl * 16;
        float bv = bias[c0 + l15];
        int wr = ntl >> 2, s = ntl & 3;
        int n = nq * 4 + s;
#pragma unroll
        for (int mt = 0; mt < 2; ++mt) {
            int rg = wave * 2 + mt;
            unsigned long long pk = 0;
#pragma unroll
            for (int r = 0; r < 4; ++r)
                pk |= ((unsigned long long)f2bf(acc[mt][ntl][r] + bv)) << (16 * r);
            *(unsigned long long*)(xz + (((size_t)(tl * 8 + rg) * 4 + wr) * 16 + n) * 256 + lane * 4) = pk;
        }
    }
}

// ---- LSTM recurrence path: i8 MFMA, U register-resident, 8 waves / 2 per SIMD ----
// block owns batch rows [4*blk, 4*blk+4); wave w covers cols (w>>1)*64+(w&1)*32 +s*16+l15.
// Raw s_barrier + lgkmcnt(0) only: hout stores / xz loads pipeline across steps
// (no per-step vmcnt(0) drain as __syncthreads would force).
__device__ __forceinline__ void rec_path(
    int blk, int tid,
    const signed char* __restrict__ Ui8,     // [1024][256] i8
    const unsigned short* __restrict__ xz,   // chunk, swizzled
    const float* __restrict__ uscale,
    unsigned short* __restrict__ hout,       // [T][128][256] bf16
    float* __restrict__ cstate,              // [32][1024] f32
    int t0) {
    __shared__ __align__(16) int zbuf[4096];                 // [w][n][l15][r] = 16 KB
    __shared__ __align__(16) signed char hbuf[2][16 * 272];  // i8 h ping-pong
    const int w = tid >> 6, lane = tid & 63, quad = lane >> 4, l15 = lane & 15;
    const int sh = quad * 16;
    const int wr = w >> 1;                       // old wave index 0..3
    const int whalf = w & 1;                     // which s-pair of the old wave
    const int colbase = wr * 64 + whalf * 32;    // + s*16 + l15 gives gate-local col

    // U fragments: 8 n-tiles x 4 kt x int4 = 128 VGPR, resident all steps
    i32x4 Bf[8][4];
#pragma unroll
    for (int n = 0; n < 8; ++n) {
        int col = (n >> 1) * 256 + colbase + (n & 1) * 16 + l15;
#pragma unroll
        for (int kt = 0; kt < 4; ++kt)
            Bf[n][kt] = *(const i32x4*)(Ui8 + (size_t)col * 256 + kt * 64 + quad * 16);
    }

    // zero both h buffers (rows 4..15 stay zero forever)
    for (int i = tid; i < 2176; i += 512) ((int*)hbuf)[i] = 0;

    float cst[2];
    if (t0 > 0) {
#pragma unroll
        for (int s = 0; s < 2; ++s) {
            int col = colbase + s * 16 + l15;
            float h = bf2f(hout[((size_t)(t0 - 1) * 128 + blk * 4 + quad) * 256 + col]);
            hbuf[0][quad * 272 + col] = (signed char)__float2int_rn(h * 127.f);
            cst[s] = cstate[(size_t)blk * 1024 + tid * 2 + s];
        }
    } else {
        cst[0] = 0.f; cst[1] = 0.f;
    }
    const float SUH = (*uscale) * (1.f / 16129.f);   // (umax/127) * (1/127)
    __syncthreads();

    const i32x4 zeroi = {0, 0, 0, 0};
    int p = 0;
#pragma unroll 1
    for (int tl = 0; tl < CH; ++tl) {
        // xz loads: no dependency, fire early (latency hidden behind MFMA)
        const unsigned short* xb = xz + (size_t)tl * 131072 + (blk >> 2) * 16384
                                      + wr * 4096 + (blk & 3) * 64 + l15 * 4;
        unsigned long long xu[8];
#pragma unroll
        for (int n = 0; n < 8; ++n) {
            int n_old = (n >> 1) * 4 + whalf * 2 + (n & 1);
            xu[n] = *(const unsigned long long*)(xb + n_old * 256);
        }

        // A fragments from i8 h ping-pong (rows 4..15 are zero padding)
        const signed char* hb = hbuf[p];
        i32x4 Af[4];
#pragma unroll
        for (int kt = 0; kt < 4; ++kt)
            Af[kt] = *(const i32x4*)(hb + l15 * 272 + kt * 64 + quad * 16);

        i32x4 acc[8];
#pragma unroll
        for (int n = 0; n < 8; ++n) acc[n] = zeroi;
#pragma unroll
        for (int kt = 0; kt < 4; ++kt) {
            i32x4 a = Af[kt];
#pragma unroll
            for (int n = 0; n < 8; ++n)
                acc[n] = __builtin_amdgcn_mfma_i32_16x16x64_i8(a, Bf[n][kt], acc[n], 0, 0, 0);
        }

        // z-exchange (wave-local: writer quad0 lanes, readers all lanes)
        if (quad == 0) {
#pragma unroll
            for (int n = 0; n < 8; ++n)
                *(i32x4*)(zbuf + ((w * 8 + n) * 16 + l15) * 4) = acc[n];
        }
        float zv[8];
#pragma unroll
        for (int n = 0; n < 8; ++n) {
            int zi = zbuf[((w * 8 + n) * 16 + l15) * 4 + quad];
            zv[n] = (float)zi * SUH + bf2f((unsigned int)(xu[n] >> sh));
        }

        // gates: this lane owns (row = quad, cols colbase + s*16 + l15)
        unsigned short* hO = hout + ((size_t)((t0 + tl) * 128 + blk * 4 + quad)) * 256 + colbase + l15;
        signed char* hw = hbuf[p ^ 1];
#pragma unroll
        for (int s = 0; s < 2; ++s) {
            float c = sigm(zv[2 + s]) * cst[s] + sigm(zv[s]) * tanh_(zv[4 + s]);
            cst[s] = c;
            float h = sigm(zv[6 + s]) * tanh_(c);
            hw[quad * 272 + colbase + s * 16 + l15] = (signed char)__float2int_rn(h * 127.f);  // LDS first
            hO[s * 16] = f2bf(h);                                                              // global: fire & forget
        }
        // LDS handoff only needs lgkmcnt; leave global stores/loads in flight.
        asm volatile("s_waitcnt lgkmcnt(0)" ::: "memory");
        __builtin_amdgcn_s_barrier();
        asm volatile("" ::: "memory");
        p ^= 1;
    }
#pragma unroll
    for (int s = 0; s < 2; ++s)
        cstate[(size_t)blk * 1024 + tid * 2 + s] = cst[s];
}

// ---- Dense(tanh) + LayerNorm path for one t (128 rows), tid 0..255 ----
__device__ __forceinline__ void dense_path(
    int t, int tid,
    const unsigned short* __restrict__ h2buf, const unsigned short* __restrict__ Wdt,
    const float* __restrict__ bd, const float* __restrict__ gamma,
    const float* __restrict__ beta, float* __restrict__ out) {
    const int wave = tid >> 6, lane = tid & 63, quad = lane >> 4, l15 = lane & 15;
    const unsigned short* A = h2buf + (size_t)t * B_ * H_;
    const f32x4 zero = {0.f, 0.f, 0.f, 0.f};

    f32x4 acc[2][16];
#pragma unroll
    for (int m = 0; m < 2; ++m)
#pragma unroll
        for (int n = 0; n < 16; ++n) acc[m][n] = zero;

#pragma unroll
    for (int kt = 0; kt < 8; ++kt) {
        bf16x8 a[2];
#pragma unroll
        for (int m = 0; m < 2; ++m) {
            int row = wave * 32 + m * 16 + l15;
            a[m] = *(const bf16x8*)(A + (size_t)row * H_ + kt * 32 + quad * 8);
        }
#pragma unroll
        for (int n = 0; n < 16; ++n) {
            bf16x8 b = *(const bf16x8*)(Wdt + (size_t)(n * 16 + l15) * H_ + kt * 32 + quad * 8);
            acc[0][n] = __builtin_amdgcn_mfma_f32_16x16x32_bf16(a[0], b, acc[0][n], 0, 0, 0);
            acc[1][n] = __builtin_amdgcn_mfma_f32_16x16x32_bf16(a[1], b, acc[1][n], 0, 0, 0);
        }
    }

    float gm[16], bt[16], bdv[16];
#pragma unroll
    for (int n = 0; n < 16; ++n) {
        int c = n * 16 + l15;
        gm[n] = gamma[c]; bt[n] = beta[c]; bdv[n] = bd[c];
    }
#pragma unroll
    for (int m = 0; m < 2; ++m) {
#pragma unroll
        for (int r = 0; r < 4; ++r) {
            float v[16], s = 0.f, sq = 0.f;
#pragma unroll
            for (int n = 0; n < 16; ++n) {
                float x = tanh_(acc[m][n][r] + bdv[n]);
                v[n] = x; s += x; sq += x * x;
            }
#pragma unroll
            for (int off = 1; off < 16; off <<= 1) {
                s += __shfl_xor(s, off);
                sq += __shfl_xor(sq, off);
            }
            float mu = s * (1.f / 256.f);
            float var = sq * (1.f / 256.f) - mu * mu;
            float rs = rsqrtf(var + 1e-3f);
            int row = wave * 32 + m * 16 + quad * 4 + r;   // batch index
            float* po = out + (size_t)row * (T_ * H_) + (size_t)t * H_;
#pragma unroll
            for (int n = 0; n < 16; ++n)
                po[n * 16 + l15] = (v[n] - mu) * rs * gm[n] + bt[n];
        }
    }
}

// ---- heterogeneous fused kernel: [0,nrec) rec | [.,+ngemm) gemm | [.,+ndense) dense.
// rec blocks fill their CU (2 waves/SIMD @ 256-reg cap), so gemm/dense blocks land on
// the other ~224 CUs and run concurrently with the serial recurrence.
__global__ __launch_bounds__(512, 2) void k_fused(
    const signed char* __restrict__ Ui8, const unsigned short* __restrict__ xzr,
    const float* __restrict__ uscale, unsigned short* __restrict__ hout,
    float* __restrict__ cstate, int t0, int nrec,
    const unsigned short* __restrict__ gA, const unsigned short* __restrict__ gBt,
    const float* __restrict__ gbias, unsigned short* __restrict__ gxz, int ngemm,
    const unsigned short* __restrict__ dH, const unsigned short* __restrict__ dWdt,
    const float* __restrict__ dbd, const float* __restrict__ dgamma,
    const float* __restrict__ dbeta, float* __restrict__ dout, int tbase, int ndense) {
    const int bid = blockIdx.x;
    const int tid = threadIdx.x;
    if (bid < nrec) {
        rec_path(bid, tid, Ui8, xzr, uscale, hout, cstate, t0);
        return;
    }
    int gb = bid - nrec;
    if (gb < ngemm) {
        // 512 threads = two old 256-thread gemm blocks
        gemm_path(gb * 2 + (tid >> 8), tid & 255, gA, gBt, gbias, gxz);
        return;
    }
    int db = gb - ngemm;
    if (db < ndense) {
        dense_path(tbase + db * 2 + (tid >> 8), tid & 255, dH, dWdt, dbd, dgamma, dbeta, dout);
    }
}

extern "C" void kernel_launch(void* const* d_in, const int* in_sizes, int n_in,
                              void* d_out, int out_size, void* d_ws, size_t ws_size,
                              hipStream_t stream) {
    const float* x     = (const float*)d_in[0];
    const float* W0    = (const float*)d_in[1];
    const float* U0    = (const float*)d_in[2];
    const float* b0    = (const float*)d_in[3];
    const float* W1    = (const float*)d_in[4];
    const float* U1    = (const float*)d_in[5];
    const float* b1    = (const float*)d_in[6];
    const float* Wd    = (const float*)d_in[7];
    const float* bd    = (const float*)d_in[8];
    const float* gamma = (const float*)d_in[9];
    const float* beta  = (const float*)d_in[10];
    float* out = (float*)d_out;

    char* ws = (char*)d_ws;
    const bool big = ws_size >= (131ull << 20);   // room for xz double buffer?

    unsigned short* buf0 = (unsigned short*)(ws);                  // 32 MB: xbf, later h2
    unsigned short* h1, *xzA, *xzB;
    size_t tail;
    if (big) {
        h1  = (unsigned short*)(ws + (32u << 20));   // 32 MB
        xzA = (unsigned short*)(ws + (64u << 20));   // 32 MB
        xzB = (unsigned short*)(ws + (96u << 20));   // 32 MB
        tail = (size_t)128 << 20;
    } else {
        xzA = (unsigned short*)(ws + (32u << 20));
        xzB = xzA;
        h1  = (unsigned short*)(ws + (64u << 20));
        tail = (size_t)96 << 20;
    }
    unsigned short* Wt0  = (unsigned short*)(ws + tail);             // 512 KB
    unsigned short* Wt1  = (unsigned short*)(ws + tail + 524288);    // 512 KB
    signed char*    Ui0  = (signed char*)  (ws + tail + 1048576);    // 256 KB
    signed char*    Ui1  = (signed char*)  (ws + tail + 1310720);    // 256 KB
    unsigned short* Wdt  = (unsigned short*)(ws + tail + 1572864);   // 128 KB
    float*          sc   = (float*)        (ws + tail + 1703936);    // 2 slots
    float*          cbuf = (float*)        (ws + tail + 1704448);    // 128 KB

    hipMemsetAsync(sc, 0, 64, stream);
    k_prep_x<<<16384, 256, 0, stream>>>(x, buf0);
    k_prep_w<<<1024, 256, 0, stream>>>(W0, Wt0);
    k_prep_w<<<1024, 256, 0, stream>>>(W1, Wt1);
    k_prep_wd<<<256, 256, 0, stream>>>(Wd, Wdt);
    k_umax<<<256, 256, 0, stream>>>(U0, sc);
    k_umax<<<256, 256, 0, stream>>>(U1, sc + 1);
    k_prep_u<<<1024, 256, 0, stream>>>(U0, sc, Ui0);
    k_prep_u<<<1024, 256, 0, stream>>>(U1, sc + 1, Ui1);

    auto launch = [&](int nrec, const signed char* Ui, const unsigned short* xzr,
                      const float* us, unsigned short* ho, int t0,
                      int ngemm, const unsigned short* gA, const unsigned short* gBt,
                      const float* gb, unsigned short* gxz,
                      int ndense, int tbase) {
        int grid = nrec + ngemm + ndense;
        k_fused<<<grid, 512, 0, stream>>>(Ui, xzr, us, ho, cbuf, t0, nrec,
                                          gA, gBt, gb, gxz, ngemm,
                                          buf0, Wdt, bd, gamma, beta, out, tbase, ndense);
    };

    if (big) {
        // L0: gemm(0,0)
        launch(0,  Ui0, xzA, sc,    h1,   0,   256, buf0,          Wt0, b0, xzA, 0, 0);
        // L1..L4: layer-0 rec overlapped with next gemm (layer-0 then layer-1 chunk 0)
        launch(RB, Ui0, xzA, sc,    h1,   0,   256, buf0 + 1 * CS, Wt0, b0, xzB, 0, 0);
        launch(RB, Ui0, xzB, sc,    h1,   128, 256, buf0 + 2 * CS, Wt0, b0, xzA, 0, 0);
        launch(RB, Ui0, xzA, sc,    h1,   256, 256, buf0 + 3 * CS, Wt0, b0, xzB, 0, 0);
        launch(RB, Ui0, xzB, sc,    h1,   384, 256, h1,            Wt1, b1, xzA, 0, 0);
        // L5..L8: layer-1 rec overlapped with layer-1 gemms and dense chunks
        launch(RB, Ui1, xzA, sc+1,  buf0, 0,   256, h1 + 1 * CS,   Wt1, b1, xzB, 0, 0);
        launch(RB, Ui1, xzB, sc+1,  buf0, 128, 256, h1 + 2 * CS,   Wt1, b1, xzA, 64, 0);
        launch(RB, Ui1, xzA, sc+1,  buf0, 256, 256, h1 + 3 * CS,   Wt1, b1, xzB, 64, 128);
        launch(RB, Ui1, xzB, sc+1,  buf0, 384, 0,   buf0,          Wt1, b1, xzA, 64, 256);
        // L9: final dense chunk
        launch(0,  Ui1, xzA, sc+1,  buf0, 0,   0,   buf0,          Wt1, b1, xzA, 64, 384);
    } else {
        // serial fallback (single xz slab)
        for (int c = 0; c < 4; ++c) {
            launch(0,  Ui0, xzA, sc,   h1, 0,      256, buf0 + (size_t)c * CS, Wt0, b0, xzA, 0, 0);
            launch(RB, Ui0, xzA, sc,   h1, c * CH, 0,   buf0, Wt0, b0, xzA, 0, 0);
        }
        for (int c = 0; c < 4; ++c) {
            launch(0,  Ui1, xzA, sc+1, buf0, 0,      256, h1 + (size_t)c * CS, Wt1, b1, xzA, 0, 0);
            launch(RB, Ui1, xzA, sc+1, buf0, c * CH, 0,   buf0, Wt1, b1, xzA, 0, 0);
        }
        launch(0, Ui1, xzA, sc+1, buf0, 0, 0, buf0, Wt1, b1, xzA, 256, 0);
    }
}

// Round 3
// 1266.551 us; speedup vs baseline: 2.2811x; 1.3963x over previous
//
#include <hip/hip_runtime.h>
#include <stdint.h>

#define B_ 128
#define T_ 512
#define H_ 256
#define CH 64            // timesteps per chunk (xz slab = 16 MB, 8 chunks/layer)
#define NC 8             // chunks per layer
#define RB 32            // rec blocks per layer (4 batch rows each)
#define CSRC ((size_t)CH * 32768)   // source chunk stride in shorts (4 MB)

typedef short bf16x8 __attribute__((ext_vector_type(8)));   // 8 bf16 = 4 VGPRs
typedef float f32x4 __attribute__((ext_vector_type(4)));
typedef int   i32x4 __attribute__((ext_vector_type(4)));

__device__ __forceinline__ unsigned short f2bf(float f) {
    union { float f; uint32_t u; } v; v.f = f;
    uint32_t u = v.u;
    return (unsigned short)((u + 0x7FFFu + ((u >> 16) & 1u)) >> 16);  // RNE
}
__device__ __forceinline__ float bf2f(unsigned int b) {
    union { uint32_t u; float f; } v; v.u = (b & 0xFFFFu) << 16; return v.f;
}
__device__ __forceinline__ float sigm(float x) { return 1.0f / (1.0f + __expf(-x)); }
__device__ __forceinline__ float tanh_(float x) { return 1.0f - 2.0f / (__expf(2.0f * x) + 1.0f); }

// ---- prep: x[b][t][f] fp32 -> xbf[t][b][f] bf16 ----
__global__ void k_prep_x(const float* __restrict__ x, unsigned short* __restrict__ xbf) {
    int idx = blockIdx.x * blockDim.x + threadIdx.x;   // over B*T*F/4
    int f4 = idx & 63;
    int t = (idx >> 6) & 511;
    int b = idx >> 15;
    float4 v = *(const float4*)(x + ((size_t)b * T_ + t) * H_ + f4 * 4);
    ushort4 o;
    o.x = f2bf(v.x); o.y = f2bf(v.y); o.z = f2bf(v.z); o.w = f2bf(v.w);
    *(ushort4*)(xbf + ((size_t)t * B_ + b) * H_ + f4 * 4) = o;
}

// ---- prep: in [256][1024] fp32 -> out[col][k] bf16 ----
__global__ void k_prep_w(const float* __restrict__ in, unsigned short* __restrict__ out) {
    int idx = blockIdx.x * blockDim.x + threadIdx.x;   // 1024*256
    int k = idx & 255; int col = idx >> 8;
    out[(size_t)col * 256 + k] = f2bf(in[(size_t)k * 1024 + col]);
}

__global__ void k_prep_wd(const float* __restrict__ Wd, unsigned short* __restrict__ Wdt) {
    int idx = blockIdx.x * blockDim.x + threadIdx.x;   // 256*256
    int k = idx & 255; int col = idx >> 8;
    Wdt[(size_t)col * 256 + k] = f2bf(Wd[(size_t)k * 256 + col]);
}

// ---- absmax of U (262144 fp32) -> slot (float bits via int atomicMax) ----
__global__ void k_umax(const float* __restrict__ in, float* __restrict__ slot) {
    float m = 0.f;
    for (int i = blockIdx.x * blockDim.x + threadIdx.x; i < 262144; i += gridDim.x * blockDim.x)
        m = fmaxf(m, fabsf(in[i]));
#pragma unroll
    for (int off = 1; off < 64; off <<= 1) m = fmaxf(m, __shfl_xor(m, off));
    if ((threadIdx.x & 63) == 0) atomicMax((int*)slot, __float_as_int(m));
}

// ---- quantize U: in [256][1024] fp32 -> out[col][k] i8 ----
__global__ void k_prep_u(const float* __restrict__ in, const float* __restrict__ umax,
                         signed char* __restrict__ out) {
    int idx = blockIdx.x * blockDim.x + threadIdx.x;   // 1024*256
    int k = idx & 255; int col = idx >> 8;
    float s = 127.f / *umax;
    float v = in[(size_t)k * 1024 + col] * s;
    out[(size_t)col * 256 + k] = (signed char)__float2int_rn(fminf(fmaxf(v, -127.f), 127.f));
}

// ================= fused-kernel device paths =================

// ---- input-projection GEMM path, one "old block" ob = (tl, nq), tid 0..255 ----
// A[tl][128][256] bf16 x Bt[1024][256] + bias -> xz swizzled bf16:
// elem addr = tl*131072 + rg*16384 + wr*4096 + n*256 + (quad*16+l15)*4 + r
__device__ __forceinline__ void gemm_path(
    int ob, int tid,
    const unsigned short* __restrict__ A, const unsigned short* __restrict__ Bt,
    const float* __restrict__ bias, unsigned short* __restrict__ xz) {
    const int tl = ob >> 2, nq = ob & 3;
    const int wave = tid >> 6, lane = tid & 63, quad = lane >> 4, l15 = lane & 15;
    const f32x4 zero = {0.f, 0.f, 0.f, 0.f};
    f32x4 acc[2][16];
#pragma unroll
    for (int m = 0; m < 2; ++m)
#pragma unroll
        for (int n = 0; n < 16; ++n) acc[m][n] = zero;

#pragma unroll
    for (int kt = 0; kt < 8; ++kt) {
        bf16x8 a0 = *(const bf16x8*)(A + ((size_t)(tl * 128 + wave * 32 + l15)) * 256 + kt * 32 + quad * 8);
        bf16x8 a1 = *(const bf16x8*)(A + ((size_t)(tl * 128 + wave * 32 + 16 + l15)) * 256 + kt * 32 + quad * 8);
#pragma unroll
        for (int ntl = 0; ntl < 16; ++ntl) {
            bf16x8 b = *(const bf16x8*)(Bt + ((size_t)(nq * 256 + ntl * 16 + l15)) * 256 + kt * 32 + quad * 8);
            acc[0][ntl] = __builtin_amdgcn_mfma_f32_16x16x32_bf16(a0, b, acc[0][ntl], 0, 0, 0);
            acc[1][ntl] = __builtin_amdgcn_mfma_f32_16x16x32_bf16(a1, b, acc[1][ntl], 0, 0, 0);
        }
    }
#pragma unroll
    for (int ntl = 0; ntl < 16; ++ntl) {
        int c0 = nq * 256 + ntl * 16;
        float bv = bias[c0 + l15];
        int wr = ntl >> 2, s = ntl & 3;
        int n = nq * 4 + s;
#pragma unroll
        for (int mt = 0; mt < 2; ++mt) {
            int rg = wave * 2 + mt;
            unsigned long long pk = 0;
#pragma unroll
            for (int r = 0; r < 4; ++r)
                pk |= ((unsigned long long)f2bf(acc[mt][ntl][r] + bv)) << (16 * r);
            *(unsigned long long*)(xz + (((size_t)(tl * 8 + rg) * 4 + wr) * 16 + n) * 256 + lane * 4) = pk;
        }
    }
}

// ---- LSTM recurrence path: i8 MFMA, U register-resident, 8 waves / 2 per SIMD ----
// block owns batch rows [4*blk, 4*blk+4); wave w covers cols (w>>1)*64+(w&1)*32 +s*16+l15.
// Raw s_barrier + lgkmcnt(0) only: hout stores / xz loads pipeline across steps.
__device__ __forceinline__ void rec_path(
    int blk, int tid,
    const signed char* __restrict__ Ui8,     // [1024][256] i8
    const unsigned short* __restrict__ xz,   // chunk slab, swizzled
    const float* __restrict__ uscale,
    unsigned short* __restrict__ hout,       // [T][128][256] bf16
    float* __restrict__ cstate,              // [32][1024] f32
    int t0) {
    __shared__ __align__(16) int zbuf[4096];                 // [w][n][l15][r] = 16 KB
    __shared__ __align__(16) signed char hbuf[2][16 * 272];  // i8 h ping-pong
    const int w = tid >> 6, lane = tid & 63, quad = lane >> 4, l15 = lane & 15;
    const int sh = quad * 16;
    const int wr = w >> 1;                       // old wave index 0..3
    const int whalf = w & 1;                     // which s-pair of the old wave
    const int colbase = wr * 64 + whalf * 32;    // + s*16 + l15 gives gate-local col

    // U fragments: 8 n-tiles x 4 kt x int4 = 128 VGPR, resident all steps
    i32x4 Bf[8][4];
#pragma unroll
    for (int n = 0; n < 8; ++n) {
        int col = (n >> 1) * 256 + colbase + (n & 1) * 16 + l15;
#pragma unroll
        for (int kt = 0; kt < 4; ++kt)
            Bf[n][kt] = *(const i32x4*)(Ui8 + (size_t)col * 256 + kt * 64 + quad * 16);
    }

    // zero both h buffers (rows 4..15 stay zero forever)
    for (int i = tid; i < 2176; i += 512) ((int*)hbuf)[i] = 0;

    float cst[2];
    if (t0 > 0) {
#pragma unroll
        for (int s = 0; s < 2; ++s) {
            int col = colbase + s * 16 + l15;
            float h = bf2f(hout[((size_t)(t0 - 1) * 128 + blk * 4 + quad) * 256 + col]);
            hbuf[0][quad * 272 + col] = (signed char)__float2int_rn(h * 127.f);
            cst[s] = cstate[(size_t)blk * 1024 + tid * 2 + s];
        }
    } else {
        cst[0] = 0.f; cst[1] = 0.f;
    }
    const float SUH = (*uscale) * (1.f / 16129.f);   // (umax/127) * (1/127)
    __syncthreads();

    const i32x4 zeroi = {0, 0, 0, 0};
    int p = 0;
#pragma unroll 1
    for (int tl = 0; tl < CH; ++tl) {
        // xz loads: no dependency, fire early (latency hidden behind MFMA)
        const unsigned short* xb = xz + (size_t)tl * 131072 + (blk >> 2) * 16384
                                      + wr * 4096 + (blk & 3) * 64 + l15 * 4;
        unsigned long long xu[8];
#pragma unroll
        for (int n = 0; n < 8; ++n) {
            int n_old = (n >> 1) * 4 + whalf * 2 + (n & 1);
            xu[n] = *(const unsigned long long*)(xb + n_old * 256);
        }

        // A fragments from i8 h ping-pong (rows 4..15 are zero padding)
        const signed char* hb = hbuf[p];
        i32x4 Af[4];
#pragma unroll
        for (int kt = 0; kt < 4; ++kt)
            Af[kt] = *(const i32x4*)(hb + l15 * 272 + kt * 64 + quad * 16);

        i32x4 acc[8];
#pragma unroll
        for (int n = 0; n < 8; ++n) acc[n] = zeroi;
#pragma unroll
        for (int kt = 0; kt < 4; ++kt) {
            i32x4 a = Af[kt];
#pragma unroll
            for (int n = 0; n < 8; ++n)
                acc[n] = __builtin_amdgcn_mfma_i32_16x16x64_i8(a, Bf[n][kt], acc[n], 0, 0, 0);
        }

        // z-exchange (wave-local: writer quad0 lanes, readers all lanes)
        if (quad == 0) {
#pragma unroll
            for (int n = 0; n < 8; ++n)
                *(i32x4*)(zbuf + ((w * 8 + n) * 16 + l15) * 4) = acc[n];
        }
        float zv[8];
#pragma unroll
        for (int n = 0; n < 8; ++n) {
            int zi = zbuf[((w * 8 + n) * 16 + l15) * 4 + quad];
            zv[n] = (float)zi * SUH + bf2f((unsigned int)(xu[n] >> sh));
        }

        // gates: this lane owns (row = quad, cols colbase + s*16 + l15)
        unsigned short* hO = hout + ((size_t)((t0 + tl) * 128 + blk * 4 + quad)) * 256 + colbase + l15;
        signed char* hw = hbuf[p ^ 1];
#pragma unroll
        for (int s = 0; s < 2; ++s) {
            float c = sigm(zv[2 + s]) * cst[s] + sigm(zv[s]) * tanh_(zv[4 + s]);
            cst[s] = c;
            float h = sigm(zv[6 + s]) * tanh_(c);
            hw[quad * 272 + colbase + s * 16 + l15] = (signed char)__float2int_rn(h * 127.f);  // LDS first
            hO[s * 16] = f2bf(h);                                                              // global: fire & forget
        }
        // LDS handoff only needs lgkmcnt; leave global stores/loads in flight.
        asm volatile("s_waitcnt lgkmcnt(0)" ::: "memory");
        __builtin_amdgcn_s_barrier();
        asm volatile("" ::: "memory");
        p ^= 1;
    }
#pragma unroll
    for (int s = 0; s < 2; ++s)
        cstate[(size_t)blk * 1024 + tid * 2 + s] = cst[s];
}

// ---- Dense(tanh) + LayerNorm path for one t (128 rows), tid 0..255 ----
__device__ __forceinline__ void dense_path(
    int t, int tid,
    const unsigned short* __restrict__ h2buf, const unsigned short* __restrict__ Wdt,
    const float* __restrict__ bd, const float* __restrict__ gamma,
    const float* __restrict__ beta, float* __restrict__ out) {
    const int wave = tid >> 6, lane = tid & 63, quad = lane >> 4, l15 = lane & 15;
    const unsigned short* A = h2buf + (size_t)t * B_ * H_;
    const f32x4 zero = {0.f, 0.f, 0.f, 0.f};

    f32x4 acc[2][16];
#pragma unroll
    for (int m = 0; m < 2; ++m)
#pragma unroll
        for (int n = 0; n < 16; ++n) acc[m][n] = zero;

#pragma unroll
    for (int kt = 0; kt < 8; ++kt) {
        bf16x8 a[2];
#pragma unroll
        for (int m = 0; m < 2; ++m) {
            int row = wave * 32 + m * 16 + l15;
            a[m] = *(const bf16x8*)(A + (size_t)row * H_ + kt * 32 + quad * 8);
        }
#pragma unroll
        for (int n = 0; n < 16; ++n) {
            bf16x8 b = *(const bf16x8*)(Wdt + (size_t)(n * 16 + l15) * H_ + kt * 32 + quad * 8);
            acc[0][n] = __builtin_amdgcn_mfma_f32_16x16x32_bf16(a[0], b, acc[0][n], 0, 0, 0);
            acc[1][n] = __builtin_amdgcn_mfma_f32_16x16x32_bf16(a[1], b, acc[1][n], 0, 0, 0);
        }
    }

    float gm[16], bt[16], bdv[16];
#pragma unroll
    for (int n = 0; n < 16; ++n) {
        int c = n * 16 + l15;
        gm[n] = gamma[c]; bt[n] = beta[c]; bdv[n] = bd[c];
    }
#pragma unroll
    for (int m = 0; m < 2; ++m) {
#pragma unroll
        for (int r = 0; r < 4; ++r) {
            float v[16], s = 0.f, sq = 0.f;
#pragma unroll
            for (int n = 0; n < 16; ++n) {
                float x = tanh_(acc[m][n][r] + bdv[n]);
                v[n] = x; s += x; sq += x * x;
            }
#pragma unroll
            for (int off = 1; off < 16; off <<= 1) {
                s += __shfl_xor(s, off);
                sq += __shfl_xor(sq, off);
            }
            float mu = s * (1.f / 256.f);
            float var = sq * (1.f / 256.f) - mu * mu;
            float rs = rsqrtf(var + 1e-3f);
            int row = wave * 32 + m * 16 + quad * 4 + r;   // batch index
            float* po = out + (size_t)row * (T_ * H_) + (size_t)t * H_;
#pragma unroll
            for (int n = 0; n < 16; ++n)
                po[n * 16 + l15] = (v[n] - mu) * rs * gm[n] + bt[n];
        }
    }
}

// ---- heterogeneous fused kernel:
// [0,nr0) rec layer0 | [.,+nr1) rec layer1 | [.,+ng0) gemm0 | [.,+ng1) gemm1 | [.,+nd) dense.
// rec blocks fill whole CUs (8 waves x 256 regs), placed first in dispatch order -> the
// two rec groups pipeline the two LSTM layers on 64 CUs while gemm/dense use the rest.
__global__ __launch_bounds__(512, 2) void k_fused(
    const signed char* __restrict__ U0i8, const unsigned short* __restrict__ xz0,
    const float* __restrict__ us0, unsigned short* __restrict__ ho0,
    float* __restrict__ cs0, int t00, int nr0,
    const signed char* __restrict__ U1i8, const unsigned short* __restrict__ xz1,
    const float* __restrict__ us1, unsigned short* __restrict__ ho1,
    float* __restrict__ cs1, int t01, int nr1,
    const unsigned short* __restrict__ g0A, const unsigned short* __restrict__ g0B,
    const float* __restrict__ g0b, unsigned short* __restrict__ g0x, int ng0,
    const unsigned short* __restrict__ g1A, const unsigned short* __restrict__ g1B,
    const float* __restrict__ g1b, unsigned short* __restrict__ g1x, int ng1,
    const unsigned short* __restrict__ dH, const unsigned short* __restrict__ dWdt,
    const float* __restrict__ dbd, const float* __restrict__ dgamma,
    const float* __restrict__ dbeta, float* __restrict__ dout, int tbase, int nd) {
    int bid = blockIdx.x;
    const int tid = threadIdx.x;
    if (bid < nr0) {
        rec_path(bid, tid, U0i8, xz0, us0, ho0, cs0, t00);
        return;
    }
    bid -= nr0;
    if (bid < nr1) {
        rec_path(bid, tid, U1i8, xz1, us1, ho1, cs1, t01);
        return;
    }
    bid -= nr1;
    if (bid < ng0) {
        gemm_path(bid * 2 + (tid >> 8), tid & 255, g0A, g0B, g0b, g0x);
        return;
    }
    bid -= ng0;
    if (bid < ng1) {
        gemm_path(bid * 2 + (tid >> 8), tid & 255, g1A, g1B, g1b, g1x);
        return;
    }
    bid -= ng1;
    if (bid < nd) {
        dense_path(tbase + bid * 2 + (tid >> 8), tid & 255, dH, dWdt, dbd, dgamma, dbeta, dout);
    }
}

extern "C" void kernel_launch(void* const* d_in, const int* in_sizes, int n_in,
                              void* d_out, int out_size, void* d_ws, size_t ws_size,
                              hipStream_t stream) {
    const float* x     = (const float*)d_in[0];
    const float* W0    = (const float*)d_in[1];
    const float* U0    = (const float*)d_in[2];
    const float* b0    = (const float*)d_in[3];
    const float* W1    = (const float*)d_in[4];
    const float* U1    = (const float*)d_in[5];
    const float* b1    = (const float*)d_in[6];
    const float* Wd    = (const float*)d_in[7];
    const float* bd    = (const float*)d_in[8];
    const float* gamma = (const float*)d_in[9];
    const float* beta  = (const float*)d_in[10];
    float* out = (float*)d_out;

    char* ws = (char*)d_ws;
    const bool big = ws_size >= (131ull << 20);

    unsigned short* buf0 = (unsigned short*)(ws);                  // 32 MB: xbf, later h2
    unsigned short* h1   = (unsigned short*)(ws + (32u << 20));    // 32 MB
    unsigned short* xz0s[2], *xz1s[2];
    size_t tail;
    if (big) {
        xz0s[0] = (unsigned short*)(ws + (64u << 20));    // 16 MB each
        xz0s[1] = (unsigned short*)(ws + (80u << 20));
        xz1s[0] = (unsigned short*)(ws + (96u << 20));
        xz1s[1] = (unsigned short*)(ws + (112u << 20));
        tail = (size_t)128 << 20;
    } else {
        xz0s[0] = (unsigned short*)(ws + (64u << 20));
        xz0s[1] = xz0s[0];
        xz1s[0] = (unsigned short*)(ws + (80u << 20));
        xz1s[1] = xz1s[0];
        tail = (size_t)96 << 20;
    }
    unsigned short* Wt0  = (unsigned short*)(ws + tail);             // 512 KB
    unsigned short* Wt1  = (unsigned short*)(ws + tail + 524288);    // 512 KB
    signed char*    Ui0  = (signed char*)  (ws + tail + 1048576);    // 256 KB
    signed char*    Ui1  = (signed char*)  (ws + tail + 1310720);    // 256 KB
    unsigned short* Wdt  = (unsigned short*)(ws + tail + 1572864);   // 128 KB
    float*          sc   = (float*)        (ws + tail + 1703936);    // 2 slots
    float*          cb0  = (float*)        (ws + tail + 1704448);    // 128 KB
    float*          cb1  = (float*)        (ws + tail + 1835520);    // 128 KB

    hipMemsetAsync(sc, 0, 64, stream);
    k_prep_x<<<16384, 256, 0, stream>>>(x, buf0);
    k_prep_w<<<1024, 256, 0, stream>>>(W0, Wt0);
    k_prep_w<<<1024, 256, 0, stream>>>(W1, Wt1);
    k_prep_wd<<<256, 256, 0, stream>>>(Wd, Wdt);
    k_umax<<<256, 256, 0, stream>>>(U0, sc);
    k_umax<<<256, 256, 0, stream>>>(U1, sc + 1);
    k_prep_u<<<1024, 256, 0, stream>>>(U0, sc, Ui0);
    k_prep_u<<<1024, 256, 0, stream>>>(U1, sc + 1, Ui1);

    // Software pipeline over launches k:
    //   gemm0(k) | rec0(k-1) | gemm1(k-2) | rec1(k-3) | dense(k-4)
    // Dependencies (all satisfied across launch boundaries, never within a launch):
    //   rec0(c) reads xz0[c&1]   <- gemm0(c)  @ k=c   (read @ k=c+1)
    //   gemm1(c) reads h1[c]     <- rec0(c)   @ k=c+1 (read @ k=c+2)
    //   rec1(c) reads xz1[c&1]   <- gemm1(c)  @ k=c+2 (read @ k=c+3)
    //   dense(c) reads buf0[c]   <- rec1(c)   @ k=c+3 (read @ k=c+4)
    //   rec1(c) overwrites buf0[c] (xbf) while gemm0(c+3) reads buf0[c+3]: disjoint.
    for (int k = 0; k < NC + 4; ++k) {
        int g0 = k, r0 = k - 1, g1 = k - 2, r1 = k - 3, d = k - 4;
        int ng0 = (g0 >= 0 && g0 < NC) ? CH * 2 : 0;   // CH*4 old blocks / 2
        int nr0 = (r0 >= 0 && r0 < NC) ? RB : 0;
        int ng1 = (g1 >= 0 && g1 < NC) ? CH * 2 : 0;
        int nr1 = (r1 >= 0 && r1 < NC) ? RB : 0;
        int nd  = (d  >= 0 && d  < NC) ? CH / 2 : 0;
        int grid = nr0 + nr1 + ng0 + ng1 + nd;
        if (grid == 0) continue;
        int g0c = g0 < 0 ? 0 : (g0 >= NC ? NC - 1 : g0);
        int r0c = r0 < 0 ? 0 : (r0 >= NC ? NC - 1 : r0);
        int g1c = g1 < 0 ? 0 : (g1 >= NC ? NC - 1 : g1);
        int r1c = r1 < 0 ? 0 : (r1 >= NC ? NC - 1 : r1);
        int dc  = d  < 0 ? 0 : (d  >= NC ? NC - 1 : d);
        k_fused<<<grid, 512, 0, stream>>>(
            Ui0, xz0s[r0c & 1], sc,     h1,   cb0, r0c * CH, nr0,
            Ui1, xz1s[r1c & 1], sc + 1, buf0, cb1, r1c * CH, nr1,
            buf0 + (size_t)g0c * CSRC, Wt0, b0, xz0s[g0c & 1], ng0,
            h1   + (size_t)g1c * CSRC, Wt1, b1, xz1s[g1c & 1], ng1,
            buf0, Wdt, bd, gamma, beta, out, dc * CH, nd);
    }
}